// Round 12
// baseline (117.094 us; speedup 1.0000x reference)
//
#include <hip/hip_runtime.h>
#include <math.h>

#define NB 4
#define CH 256
#define NHEADS 4
#define HC 64
#define NT 2304    // 48*48
#define KSEG 1152  // keys per segment (2 segments)
#define NSEG 18    // 64-key chunks per segment
#define QTILE 128  // queries per block

typedef _Float16 f16;
typedef _Float16 f16x4 __attribute__((ext_vector_type(4)));
typedef _Float16 f16x8 __attribute__((ext_vector_type(8)));
typedef float f32x4 __attribute__((ext_vector_type(4)));
typedef float f32x16 __attribute__((ext_vector_type(16)));

#define MFMA16(a, b, c) __builtin_amdgcn_mfma_f32_16x16x32_f16(a, b, c, 0, 0, 0)
#define MFMA32(a, b, c) __builtin_amdgcn_mfma_f32_32x32x16_f16(a, b, c, 0, 0, 0)

__device__ __forceinline__ void gload_lds16(const void* g, void* l) {
    __builtin_amdgcn_global_load_lds(
        (const __attribute__((address_space(1))) unsigned int*)g,
        (__attribute__((address_space(3))) unsigned int*)l, 16, 0, 0);
}

__device__ __forceinline__ unsigned pkh(float a, float b) {
    auto r = __builtin_amdgcn_cvt_pkrtz(a, b);   // __fp16 ext_vector(2)
    return __builtin_bit_cast(unsigned, r);
}
// v_permlane32_swap_b32: new_a = [a.lo32 | b.lo32_old], new_b = [a.hi32_old | b.hi32]
__device__ __forceinline__ void swap32(unsigned& a, unsigned& b) {
    asm volatile("v_permlane32_swap_b32 %0, %1" : "+v"(a), "+v"(b));
}

// ---------------------------------------------------------------------------
// Fused K/Q/V projection reading x directly (unchanged from R9-R11).
// grid (36, 3, 4), block 256. Outputs: K,Q [b][h][n][64c]; V [b][h][64c][n].
// ---------------------------------------------------------------------------
__global__ __launch_bounds__(256) void proj_qkv_mfma(
    const float* __restrict__ wk, const float* __restrict__ bk,
    const float* __restrict__ wq, const float* __restrict__ bq,
    const float* __restrict__ wv, const float* __restrict__ bv,
    const float* __restrict__ X,
    f16* __restrict__ Kt, f16* __restrict__ Qt, f16* __restrict__ Vg)
{
    const int t = threadIdx.x, l = t & 63, w = t >> 6;
    const int lm = l & 15, lg = l >> 4;
    const int n0 = blockIdx.x * 64;
    const int sel = blockIdx.y;
    const int b = blockIdx.z;

    const float* W  = sel == 0 ? wk : (sel == 1 ? wq : wv);
    const float* Bi = sel == 0 ? bk : (sel == 1 ? bq : bv);

    f32x4 acc[4][4] = {};   // [h][nt]

#pragma unroll 2
    for (int ks = 0; ks < 8; ++ks) {
        f16x8 bf[4];
#pragma unroll
        for (int nt = 0; nt < 4; ++nt) {
            const float* xp = &X[((size_t)b * CH + ks * 32 + lg * 8) * NT
                                 + n0 + nt * 16 + lm];
            f16x8 v;
#pragma unroll
            for (int j = 0; j < 8; ++j) v[j] = (f16)xp[(size_t)j * NT];
            bf[nt] = v;
        }
#pragma unroll
        for (int h = 0; h < 4; ++h) {
            const float* wp = &W[(size_t)(h * 64 + w * 16 + lm) * CH + ks * 32 + lg * 8];
            const float4 wa = *reinterpret_cast<const float4*>(wp);
            const float4 wb = *reinterpret_cast<const float4*>(wp + 4);
            const f16x8 a = {(f16)wa.x, (f16)wa.y, (f16)wa.z, (f16)wa.w,
                             (f16)wb.x, (f16)wb.y, (f16)wb.z, (f16)wb.w};
#pragma unroll
            for (int nt = 0; nt < 4; ++nt)
                acc[h][nt] = MFMA16(a, bf[nt], acc[h][nt]);
        }
    }

    const int c_base = w * 16 + lg * 4;
#pragma unroll
    for (int h = 0; h < 4; ++h) {
        const float4 b4 = *reinterpret_cast<const float4*>(&Bi[h * 64 + c_base]);
        const float bb[4] = {b4.x, b4.y, b4.z, b4.w};
        if (sel < 2) {
            f16* Out = sel == 0 ? Kt : Qt;
#pragma unroll
            for (int nt = 0; nt < 4; ++nt) {
                const int n = n0 + nt * 16 + lm;
                f16x4 o = {(f16)(acc[h][nt][0] + bb[0]), (f16)(acc[h][nt][1] + bb[1]),
                           (f16)(acc[h][nt][2] + bb[2]), (f16)(acc[h][nt][3] + bb[3])};
                *reinterpret_cast<f16x4*>(
                    &Out[((size_t)((b * NHEADS + h) * NT + n)) * HC + c_base]) = o;
            }
        } else {
#pragma unroll
            for (int nt = 0; nt < 4; ++nt) {
                const int n = n0 + nt * 16 + lm;
#pragma unroll
                for (int r = 0; r < 4; ++r)
                    Vg[((size_t)((b * NHEADS + h) * HC + c_base + r)) * NT + n] =
                        (f16)(acc[h][nt][r] + bb[r]);
            }
        }
    }
}

// ---------------------------------------------------------------------------
// Flash attention, 32x32x16 MFMA, QTILE=128 (halved staging redundancy).
// Block 512 thr = 8 waves = (4 q-groups of 32) x (2 k-segments of 1152).
// Per block: stage K/V chunk once per round, shared by 4 q-groups -> total
// staged bytes HALVED vs QTILE=64 (166 MB vs 331 MB). Per-wave inner loop
// identical to R11 (swizzled gload_lds staging, in-reg P via pkrtz+permlane,
// defer-max THR=8). 2-way segment merge: sg=1 publishes partials to LDS,
// sg=0 merges in-register and stores. grid 288 = (18 q-tiles)x(16 bh),
// XCD decode: xcd = bid&7 owns 2 (b,h) pairs -> L2-resident K/V.
// ---------------------------------------------------------------------------
__global__ __launch_bounds__(512) void attn_q128(
    const f16* __restrict__ Kt, const f16* __restrict__ Qt,
    const f16* __restrict__ Vg, f16* __restrict__ Ot)
{
    __shared__ f16 SMK[2][4096];     // [seg][64 keys x 64c] 8KB each
    __shared__ f16 SMV[2][4096];     // [seg][64 c x 64k]
    __shared__ float Mst[4][32], Lst[4][32];

    const int t = threadIdx.x, l = t & 63, w = t >> 6;
    const int col = l & 31, hi = l >> 5;
    const int qg = w & 3, sg = w >> 2;   // q-group (0..3), key segment (0..1)

    const int bid = blockIdx.x;
    const int xcd = bid & 7, idx = bid >> 3;          // 36 blocks per XCD
    const int bh  = 2 * xcd + (idx >= 18 ? 1 : 0);    // 2 (b,h) pairs per XCD
    const int qt  = idx >= 18 ? idx - 18 : idx;
    const int b = bh >> 2, h = bh & 3;
    const int m0 = qt * QTILE;

    const size_t bhs = (size_t)(b * NHEADS + h);
    const f16* Kb = Kt + bhs * NT * HC;   // [n][64c] rows of 128 B
    const f16* Qb = Qt + bhs * NT * HC;
    const f16* Vb = Vg + bhs * HC * NT;   // [c][n]

    const int srow = l >> 3, su = l & 7, sx = su ^ srow;

    // resident Q B-frags: col = query, k = cs*16 + hi*8 + j
    const int q = m0 + qg * 32 + col;
    f16x8 qf[4];
#pragma unroll
    for (int cs = 0; cs < 4; ++cs)
        qf[cs] = *reinterpret_cast<const f16x8*>(
            &Qb[(size_t)q * HC + cs * 16 + hi * 8]);

    const f32x16 Z16 = {0,0,0,0,0,0,0,0,0,0,0,0,0,0,0,0};
    f32x16 acc0 = Z16, acc1 = Z16;
    float m_run = -3.0e38f, l_run = 0.0f;

    const int kbase = sg * KSEG;

    // stage chunk [kc, kc+64) of segment sg; role split across the 4 waves
    // of this segment: qg0/qg1 -> K rows 0-31/32-63, qg2/qg3 -> V likewise.
    // 4 gload_lds per wave per round.
    auto stage = [&](int kc) {
        const int half = (qg & 1) * 32;
        if (qg < 2) {
            const char* src = (const char*)(Kb + (size_t)kc * HC);
            char* dst = (char*)&SMK[sg][0];
#pragma unroll
            for (int g = 0; g < 4; ++g) {
                const int rb = half + g * 8;
                gload_lds16(src + (size_t)(rb + srow) * 128 + (sx << 4),
                            dst + rb * 128);
            }
        } else {
            const char* src = (const char*)Vb + (size_t)kc * 2;
            char* dst = (char*)&SMV[sg][0];
#pragma unroll
            for (int g = 0; g < 4; ++g) {
                const int rb = half + g * 8;
                gload_lds16(src + (size_t)(rb + srow) * (NT * 2) + (sx << 4),
                            dst + rb * 128);
            }
        }
    };

    // swizzled LDS read: 16B unit u of row stored at u ^ (row&7)
    auto rd = [&](const f16* base, int row, int u) -> f16x8 {
        return *reinterpret_cast<const f16x8*>(
            base + row * 64 + ((u ^ (row & 7)) << 3));
    };

    stage(kbase);
    __syncthreads();

    for (int i = 0; i < NSEG; ++i) {
        const f16* Kc = &SMK[sg][0];
        const f16* Vc = &SMV[sg][0];

        // ---- QK^T: S[key][query]; A=K rows (key), B=Q -------------------
        f32x16 s0 = Z16, s1 = Z16;
#pragma unroll
        for (int cs = 0; cs < 4; ++cs) {
            const f16x8 k0 = rd(Kc, col,      cs * 2 + hi);
            const f16x8 k1 = rd(Kc, 32 + col, cs * 2 + hi);
            s0 = MFMA32(k0, qf[cs], s0);
            s1 = MFMA32(k1, qf[cs], s1);
        }

        // ---- softmax over this chunk (query = col), tree reductions -----
        float m8[8];
#pragma unroll
        for (int j = 0; j < 8; ++j)
            m8[j] = fmaxf(fmaxf(s0[2 * j], s0[2 * j + 1]),
                          fmaxf(s1[2 * j], s1[2 * j + 1]));
        float cm = fmaxf(fmaxf(fmaxf(m8[0], m8[1]), fmaxf(m8[2], m8[3])),
                         fmaxf(fmaxf(m8[4], m8[5]), fmaxf(m8[6], m8[7])));
        cm = fmaxf(cm, __shfl_xor(cm, 32));
        if (!__all(cm <= m_run + 8.0f)) {     // defer-max, THR=8
            const float mN = fmaxf(m_run, cm);
            const float fac = __expf(m_run - mN);
#pragma unroll
            for (int r = 0; r < 16; ++r) { acc0[r] *= fac; acc1[r] *= fac; }
            l_run *= fac;
            m_run = mN;
        }
        float p0[16], p1[16];
        float ps0 = 0.f, ps1 = 0.f, ps2 = 0.f, ps3 = 0.f;
#pragma unroll
        for (int r = 0; r < 4; ++r) {
            p0[r]      = __expf(s0[r]      - m_run); ps0 += p0[r];
            p0[r + 4]  = __expf(s0[r + 4]  - m_run); ps1 += p0[r + 4];
            p0[r + 8]  = __expf(s0[r + 8]  - m_run); ps2 += p0[r + 8];
            p0[r + 12] = __expf(s0[r + 12] - m_run); ps3 += p0[r + 12];
            p1[r]      = __expf(s1[r]      - m_run); ps0 += p1[r];
            p1[r + 4]  = __expf(s1[r + 4]  - m_run); ps1 += p1[r + 4];
            p1[r + 8]  = __expf(s1[r + 8]  - m_run); ps2 += p1[r + 8];
            p1[r + 12] = __expf(s1[r + 12] - m_run); ps3 += p1[r + 12];
        }
        l_run += (ps0 + ps1) + (ps2 + ps3);

        // ---- P -> f16 B-frags in-register (pkrtz + permlane32_swap) -----
        unsigned a0[8], a1[8];
#pragma unroll
        for (int j = 0; j < 8; ++j) {
            a0[j] = pkh(p0[2 * j], p0[2 * j + 1]);
            a1[j] = pkh(p1[2 * j], p1[2 * j + 1]);
        }
        swap32(a0[0], a0[2]); swap32(a0[1], a0[3]);   // keys 0-15
        swap32(a0[4], a0[6]); swap32(a0[5], a0[7]);   // keys 16-31
        swap32(a1[0], a1[2]); swap32(a1[1], a1[3]);   // keys 32-47
        swap32(a1[4], a1[6]); swap32(a1[5], a1[7]);   // keys 48-63
        union BU { unsigned u[4]; f16x8 v; };
        BU fr[4];
        fr[0].u[0] = a0[0]; fr[0].u[1] = a0[1]; fr[0].u[2] = a0[2]; fr[0].u[3] = a0[3];
        fr[1].u[0] = a0[4]; fr[1].u[1] = a0[5]; fr[1].u[2] = a0[6]; fr[1].u[3] = a0[7];
        fr[2].u[0] = a1[0]; fr[2].u[1] = a1[1]; fr[2].u[2] = a1[2]; fr[2].u[3] = a1[3];
        fr[3].u[0] = a1[4]; fr[3].u[1] = a1[5]; fr[3].u[2] = a1[6]; fr[3].u[3] = a1[7];

        // ---- O += V @ P: A=V rows (channel), B=P ------------------------
#pragma unroll
        for (int kk = 0; kk < 4; ++kk) {
            const f16x8 v0 = rd(Vc, col,      kk * 2 + hi);
            const f16x8 v1 = rd(Vc, 32 + col, kk * 2 + hi);
            acc0 = MFMA32(v0, fr[kk].v, acc0);
            acc1 = MFMA32(v1, fr[kk].v, acc1);
        }

        __syncthreads();                       // all waves done with buffer
        if (i + 1 < NSEG) {
            stage(kbase + (i + 1) * 64);       // overwrite with next chunk
            __syncthreads();                   // staged (vmcnt drained)
        }
    }

    // ---- 2-way merge: sg=1 publishes partials; sg=0 merges + stores -----
    float* Part = (float*)&SMK[0][0];   // reuse 32KB: [4 qg][32 col][64 ch]
    const float l_full = l_run + __shfl_xor(l_run, 32);
    __syncthreads();   // compute done everywhere before overwriting SM
    if (sg == 1) {
        if (hi == 0) { Mst[qg][col] = m_run; Lst[qg][col] = l_full; }
        float* row = Part + ((size_t)(qg * 32 + col)) * 64;
#pragma unroll
        for (int rq = 0; rq < 4; ++rq) {
            const int c0 = rq * 8 + hi * 4;
            f32x4 o0 = {acc0[rq * 4 + 0], acc0[rq * 4 + 1],
                        acc0[rq * 4 + 2], acc0[rq * 4 + 3]};
            f32x4 o1 = {acc1[rq * 4 + 0], acc1[rq * 4 + 1],
                        acc1[rq * 4 + 2], acc1[rq * 4 + 3]};
            *reinterpret_cast<f32x4*>(row + c0) = o0;
            *reinterpret_cast<f32x4*>(row + 32 + c0) = o1;
        }
    }
    __syncthreads();
    if (sg == 0) {
        const float mB = Mst[qg][col], lB = Lst[qg][col];
        const float M = fmaxf(m_run, mB);
        const float wA = __expf(m_run - M), wB = __expf(mB - M);
        const float inv = 1.0f / (wA * l_full + wB * lB);
        const float* row = Part + ((size_t)(qg * 32 + col)) * 64;
        f16* dst = &Ot[((size_t)(b * NT + q)) * CH + h * HC];
#pragma unroll
        for (int rq = 0; rq < 4; ++rq) {
            const int c0 = rq * 8 + hi * 4;
            f16x4 o0 = {(f16)((wA * acc0[rq * 4 + 0] + wB * row[c0 + 0]) * inv),
                        (f16)((wA * acc0[rq * 4 + 1] + wB * row[c0 + 1]) * inv),
                        (f16)((wA * acc0[rq * 4 + 2] + wB * row[c0 + 2]) * inv),
                        (f16)((wA * acc0[rq * 4 + 3] + wB * row[c0 + 3]) * inv)};
            f16x4 o1 = {(f16)((wA * acc1[rq * 4 + 0] + wB * row[32 + c0 + 0]) * inv),
                        (f16)((wA * acc1[rq * 4 + 1] + wB * row[32 + c0 + 1]) * inv),
                        (f16)((wA * acc1[rq * 4 + 2] + wB * row[32 + c0 + 2]) * inv),
                        (f16)((wA * acc1[rq * 4 + 3] + wB * row[32 + c0 + 3]) * inv)};
            *reinterpret_cast<f16x4*>(dst + c0) = o0;
            *reinterpret_cast<f16x4*>(dst + 32 + c0) = o1;
        }
    }
}

// ---------------------------------------------------------------------------
// Final conv1x1 (unchanged). grid (36, 4, 4).
// ---------------------------------------------------------------------------
__global__ __launch_bounds__(256) void out_gemm_mfma(
    const float* __restrict__ wo, const float* __restrict__ bo,
    const f16* __restrict__ Ot, float* __restrict__ Y)
{
    const int t = threadIdx.x, l = t & 63, w = t >> 6;
    const int lm = l & 15, lg = l >> 4;
    const int n0 = blockIdx.x * 64;
    const int o0 = blockIdx.y * 64;
    const int b = blockIdx.z;

    f32x4 acc[4] = {{0.f,0.f,0.f,0.f},{0.f,0.f,0.f,0.f},
                    {0.f,0.f,0.f,0.f},{0.f,0.f,0.f,0.f}};
    const int o_row = o0 + w * 16 + lm;

#pragma unroll
    for (int ks = 0; ks < 8; ++ks) {
        const float* wp = &wo[(size_t)o_row * CH + ks * 32 + lg * 8];
        const float4 wa = *reinterpret_cast<const float4*>(wp);
        const float4 wb = *reinterpret_cast<const float4*>(wp + 4);
        const f16x8 a = {(f16)wa.x, (f16)wa.y, (f16)wa.z, (f16)wa.w,
                         (f16)wb.x, (f16)wb.y, (f16)wb.z, (f16)wb.w};
#pragma unroll
        for (int nt = 0; nt < 4; ++nt) {
            const f16x8 bf = *reinterpret_cast<const f16x8*>(
                &Ot[((size_t)(b * NT + n0 + nt * 16 + lm)) * CH + ks * 32 + lg * 8]);
            acc[nt] = MFMA16(a, bf, acc[nt]);
        }
    }

    const int ob = o0 + w * 16 + lg * 4;
    const float4 bias4 = *reinterpret_cast<const float4*>(&bo[ob]);
    const float bb[4] = {bias4.x, bias4.y, bias4.z, bias4.w};
#pragma unroll
    for (int nt = 0; nt < 4; ++nt) {
        const int n = n0 + nt * 16 + lm;
#pragma unroll
        for (int r = 0; r < 4; ++r)
            Y[((size_t)(b * CH + ob + r)) * NT + n] = acc[nt][r] + bb[r];
    }
}

// ---------------------------------------------------------------------------
extern "C" void kernel_launch(void* const* d_in, const int* in_sizes, int n_in,
                              void* d_out, int out_size, void* d_ws, size_t ws_size,
                              hipStream_t stream) {
    (void)in_sizes; (void)n_in; (void)out_size; (void)ws_size;
    const float* x  = (const float*)d_in[0];
    const float* wk = (const float*)d_in[1];
    const float* bk = (const float*)d_in[2];
    const float* wq = (const float*)d_in[3];
    const float* bq = (const float*)d_in[4];
    const float* wv = (const float*)d_in[5];
    const float* bv = (const float*)d_in[6];
    const float* wo = (const float*)d_in[7];
    const float* bo = (const float*)d_in[8];
    float* out = (float*)d_out;

    const size_t SZ = (size_t)NB * NT * CH;   // halves per tensor
    f16* Kt = (f16*)d_ws;        // [b][h][n][c]
    f16* Qt = Kt + SZ;           // [b][h][n][c]
    f16* Vg = Qt + SZ;           // [b][h][c][n]
    f16* Ot = Vg + SZ;           // [b][n][c]

    proj_qkv_mfma<<<dim3(36, 3, 4), 256, 0, stream>>>(
        wk, bk, wq, bq, wv, bv, x, Kt, Qt, Vg);
    attn_q128<<<dim3(288), 512, 0, stream>>>(Kt, Qt, Vg, Ot);
    out_gemm_mfma<<<dim3(36, 4, 4), 256, 0, stream>>>(wo, bo, Ot, out);
}